// Round 3
// baseline (1087.969 us; speedup 1.0000x reference)
//
#include <hip/hip_runtime.h>
#include <math.h>

// out[n,o] = exp(-max(||x_n||^2 + ||c_o||^2 - 2 x.c, 0) * inv_sigma2[o])
// N=524288, IN=3, OUT=512. Output 1.074 GB fp32 -> write-BW-bound (~171us floor).

constexpr int OUTF = 512;

__global__ __launch_bounds__(256) void rbf_kernel(
    const float* __restrict__ x,
    const float* __restrict__ centres,
    const float* __restrict__ log_sigmas,
    float* __restrict__ out,
    int nPairs)
{
    const int t = threadIdx.x;
    const int rowSub = t >> 7;        // 0 or 1: which of the block's 2 rows
    const int o = (t & 127) * 4;      // this thread's 4 output features

    // Hoist this thread's 4 centres into registers: no LDS in hot loop.
    float cx[4], cy[4], cz[4], cw[4], inv[4];
    #pragma unroll
    for (int j = 0; j < 4; ++j) {
        float a = centres[(o + j) * 3 + 0];
        float b = centres[(o + j) * 3 + 1];
        float c = centres[(o + j) * 3 + 2];
        cx[j] = a; cy[j] = b; cz[j] = c;
        cw[j] = a * a + b * b + c * c;
        inv[j] = expf(-2.0f * log_sigmas[o + j]);   // sigma^-2
    }

    for (int pair = blockIdx.x; pair < nPairs; pair += gridDim.x) {
        const int row = pair * 2 + rowSub;
        // Wave-uniform row -> these 3 loads broadcast from L1/L2.
        const float x0 = x[row * 3 + 0];
        const float x1 = x[row * 3 + 1];
        const float x2 = x[row * 3 + 2];
        const float xx = x0 * x0 + x1 * x1 + x2 * x2;

        float rr[4];
        #pragma unroll
        for (int j = 0; j < 4; ++j) {
            float sq = xx + cw[j] - 2.0f * (cx[j] * x0 + cy[j] * x1 + cz[j] * x2);
            sq = fmaxf(sq, 0.0f);
            rr[j] = __expf(-sq * inv[j]);   // == exp(-(sqrt(sq)/sigma)^2)
        }
        float4 r;
        r.x = rr[0]; r.y = rr[1]; r.z = rr[2]; r.w = rr[3];
        *reinterpret_cast<float4*>(out + (size_t)row * OUTF + o) = r;
    }
}

extern "C" void kernel_launch(void* const* d_in, const int* in_sizes, int n_in,
                              void* d_out, int out_size, void* d_ws, size_t ws_size,
                              hipStream_t stream) {
    const float* x          = (const float*)d_in[0];
    const float* centres    = (const float*)d_in[1];
    const float* log_sigmas = (const float*)d_in[2];
    float* out              = (float*)d_out;

    const int n = in_sizes[0] / 3;       // 524288 rows
    const int nPairs = n / 2;            // 2 rows per block-iteration
    const int grid = 2048;               // grid-stride; ~128 iters/block

    rbf_kernel<<<grid, 256, 0, stream>>>(x, centres, log_sigmas, out, nPairs);
}